// Round 18
// baseline (78.269 us; speedup 1.0000x reference)
//
#include <hip/hip_runtime.h>
#include <hip/hip_bf16.h>

#define B_ 4
#define N_ 2048
#define D_ 1024
#define H_ 8
#define HD_ 128

typedef __attribute__((ext_vector_type(4))) float f32x4;
typedef __attribute__((ext_vector_type(8))) short bf16x8;

__device__ __forceinline__ short f2bf(float f) {
    unsigned u = __builtin_bit_cast(unsigned, f);
    u = (u + 0x7FFFu + ((u >> 16) & 1u)) >> 16;   // round-to-nearest-even
    return (short)u;
}
__device__ __forceinline__ float bf2f(unsigned short s) {
    unsigned u = (unsigned)s << 16;
    return __builtin_bit_cast(float, u);
}

typedef const __attribute__((address_space(1))) void* gas_t;
typedef __attribute__((address_space(3))) void* las_t;

__device__ __forceinline__ void gload16(const void* g, void* l) {
    // lane i's 16B from per-lane g -> wave-uniform LDS base + lane*16
    __builtin_amdgcn_global_load_lds((gas_t)g, (las_t)l, 16, 0, 0);
}

// ---------------------------------------------------------------------------
// Kernel 0: fp32 -> bf16 pack for h (4096 blocks) and Wr (512 blocks), fused.
// ---------------------------------------------------------------------------
__global__ __launch_bounds__(256) void k_cvt(
    const float* __restrict__ h, short* __restrict__ hb,
    const float* __restrict__ Wr, short* __restrict__ wrb)
{
    int blk = blockIdx.x;
    const float* src;
    short* dst;
    int i;
    if (blk < 4096) { src = h;  dst = hb;  i = blk * 256 + threadIdx.x; }
    else            { src = Wr; dst = wrb; i = (blk - 4096) * 256 + threadIdx.x; }
    float4 a = ((const float4*)src)[i * 2];
    float4 b = ((const float4*)src)[i * 2 + 1];
    bf16x8 o;
    o[0] = f2bf(a.x); o[1] = f2bf(a.y); o[2] = f2bf(a.z); o[3] = f2bf(a.w);
    o[4] = f2bf(b.x); o[5] = f2bf(b.y); o[6] = f2bf(b.z); o[7] = f2bf(b.w);
    ((bf16x8*)dst)[i] = o;
}

// ---------------------------------------------------------------------------
// Kernel 1: GEMM fr = h @ Wr^T, 64x128 tile, BK=32, double-buffered with
// COUNTED vmcnt + raw s_barrier (T4 pattern). __syncthreads() drains
// vmcnt(0) -- it waited for the prefetch loads too, which is why every
// previous dbuf variant was neutral. Here prefetch loads stay in flight
// across both barriers:
//   prologue: STAGE(buf0,k0); STAGE(buf1,k1)            // 6 outstanding
//   loop:     vmcnt(3); s_barrier                        // buf[t] landed
//             ds_read+MFMA(buf[t])                       // lgkm auto
//             s_barrier                                  // reads complete
//             STAGE(buf[t&1], t+2)                       // back to 6
// Safety: per-wave vmcnt + barrier => all waves' LDS writes visible; each
// wave's lgkmcnt(0) precedes its MFMAs so ds_reads are complete before the
// post-compute barrier => re-staging cannot overwrite live data.
// Grid = 128 row-tiles x 8 heads = 1024 blocks (4/CU).
// Fused epilogue: sr[b,head,j] = sum_c leaky(fr[j, head*128+c]) * att_r[c]
// ---------------------------------------------------------------------------
__global__ __launch_bounds__(256) void k_proj_sr(
    const short* __restrict__ hb, const short* __restrict__ wrb,
    const float* __restrict__ att_r, float* __restrict__ sr)
{
    __shared__ short sA[2][64 * 32];    // 2 x 4 KB
    __shared__ short sB[2][128 * 32];   // 2 x 8 KB
    __shared__ float part[4][64];

    const int tid  = threadIdx.x;
    const int lane = tid & 63;
    const int wave = tid >> 6;         // 0..3 = column group (32 cols each)
    const int cc   = lane & 15;
    const int g    = lane >> 4;
    const int rowBase = blockIdx.x * 64;    // 0..8191 step 64
    const int head    = blockIdx.y;

    const int srow = lane >> 2;                       // 0..15
    const int scol = (lane & 3) * 8;                  // bf16 elems
    const short* gA0 = hb  + (size_t)(rowBase + wave * 16 + srow) * D_ + scol;
    const short* gB0 = wrb + (size_t)(head * HD_ + wave * 32 + srow) * D_ + scol;
    const short* gB1 = gB0 + (size_t)16 * D_;
    const int offA = wave * 1024;      // bytes within a buffer
    const int offB = wave * 2048;

    f32x4 acc[4][2];
#pragma unroll
    for (int m = 0; m < 4; ++m)
#pragma unroll
        for (int n = 0; n < 2; ++n) acc[m][n] = (f32x4){0.f, 0.f, 0.f, 0.f};

    auto STAGE = [&](int bufidx, int kk) {
        gload16(gA0 + kk, (char*)sA[bufidx] + offA);
        gload16(gB0 + kk, (char*)sB[bufidx] + offB);
        gload16(gB1 + kk, (char*)sB[bufidx] + offB + 1024);
    };
    auto COMPUTE = [&](int cur) {
        const short* bufA = sA[cur];
        const short* bufB = sB[cur];
        bf16x8 aF[4], bF[2];
#pragma unroll
        for (int m = 0; m < 4; ++m)
            aF[m] = *(const bf16x8*)(bufA + (m * 16 + cc) * 32 + g * 8);
#pragma unroll
        for (int n = 0; n < 2; ++n)
            bF[n] = *(const bf16x8*)(bufB + (wave * 32 + n * 16 + cc) * 32 + g * 8);
        __builtin_amdgcn_s_setprio(1);
#pragma unroll
        for (int m = 0; m < 4; ++m)
#pragma unroll
            for (int n = 0; n < 2; ++n)
                acc[m][n] = __builtin_amdgcn_mfma_f32_16x16x32_bf16(
                    aF[m], bF[n], acc[m][n], 0, 0, 0);
        __builtin_amdgcn_s_setprio(0);
    };

    // prologue: stage K-steps 0,1 into buffers 0,1 (6 loads outstanding)
    STAGE(0, 0);
    STAGE(1, 32);

    for (int t = 0; t < 31; ++t) {
        asm volatile("s_waitcnt vmcnt(3)" ::: "memory");  // buf[t] landed
        __builtin_amdgcn_s_barrier();
        __builtin_amdgcn_sched_barrier(0);
        COMPUTE(t & 1);
        __builtin_amdgcn_sched_barrier(0);
        __builtin_amdgcn_s_barrier();    // all waves' ds_reads of buf[t] done
        if (t < 30) STAGE(t & 1, (t + 2) * 32);
    }
    asm volatile("s_waitcnt vmcnt(0)" ::: "memory");
    __builtin_amdgcn_s_barrier();
    __builtin_amdgcn_sched_barrier(0);
    COMPUTE(1);                          // t = 31

    // Epilogue: row = rowBase + m*16 + g*4 + r, col = wave*32 + n*16 + cc
    float ar[2];
#pragma unroll
    for (int n = 0; n < 2; ++n) ar[n] = att_r[wave * 32 + n * 16 + cc];

#pragma unroll
    for (int m = 0; m < 4; ++m) {
#pragma unroll
        for (int r = 0; r < 4; ++r) {
            float p = 0.f;
#pragma unroll
            for (int n = 0; n < 2; ++n) {
                float v = acc[m][n][r];
                v = v > 0.f ? v : 0.01f * v;    // leaky
                p += v * ar[n];
            }
            p += __shfl_xor(p, 1); p += __shfl_xor(p, 2);
            p += __shfl_xor(p, 4); p += __shfl_xor(p, 8);
            if (cc == 0) part[wave][m * 16 + g * 4 + r] = p;
        }
    }
    __syncthreads();
    if (tid < 64) {
        const int grow = rowBase + tid;
        const int b = grow >> 11, j = grow & (N_ - 1);
        sr[(size_t)(b * H_ + head) * N_ + j] =
            part[0][tid] + part[1][tid] + part[2][tid] + part[3][tid];
    }
}

// ---------------------------------------------------------------------------
// Kernel 2: hbar partials with inline softmax stats (L2-resident sr).
//   hp[jc*32 + b*8 + h][d] = sum_{j in chunk jc} exp(sr-mx)/sum * hb[b,j,d]
// Grid dim3(4 dc, 16 jc, 4 b) = 256 blocks.
// ---------------------------------------------------------------------------
__global__ __launch_bounds__(256) void k_hbar(
    const short* __restrict__ hbm, const float* __restrict__ sr,
    float* __restrict__ hp)
{
    const int dc = blockIdx.x;   // 0..3
    const int jc = blockIdx.y;   // 0..15  (128 j each)
    const int b  = blockIdx.z;   // 0..3
    const int tid = threadIdx.x;
    const int d = dc * 256 + tid;

    __shared__ float smx[8], sism[8];
    {
        const int hh = tid >> 5;
        const int sl = tid & 31;
        const float4* row = (const float4*)(sr + (size_t)(b * H_ + hh) * N_);
        float4 v[16];
        float mx = -1e30f;
#pragma unroll
        for (int k = 0; k < 16; ++k) {
            v[k] = row[sl + k * 32];
            mx = fmaxf(fmaxf(mx, fmaxf(v[k].x, v[k].y)), fmaxf(v[k].z, v[k].w));
        }
#pragma unroll
        for (int m = 1; m < 32; m <<= 1) mx = fmaxf(mx, __shfl_xor(mx, m));
        float sum = 0.f;
#pragma unroll
        for (int k = 0; k < 16; ++k)
            sum += expf(v[k].x - mx) + expf(v[k].y - mx) +
                   expf(v[k].z - mx) + expf(v[k].w - mx);
#pragma unroll
        for (int m = 1; m < 32; m <<= 1) sum += __shfl_xor(sum, m);
        if (sl == 0) { smx[hh] = mx; sism[hh] = 1.f / sum; }
    }
    __syncthreads();

    __shared__ float wl[8][128];
    for (int idx = tid; idx < 1024; idx += 256) {
        const int hh = idx >> 7, jj = idx & 127;
        wl[hh][jj] = expf(sr[(size_t)(b * H_ + hh) * N_ + jc * 128 + jj]
                          - smx[hh]) * sism[hh];
    }
    __syncthreads();

    float acc[8] = {0.f, 0.f, 0.f, 0.f, 0.f, 0.f, 0.f, 0.f};
    const short* hp0 = hbm + ((size_t)(b * N_ + jc * 128)) * D_ + d;
#pragma unroll 4
    for (int jj = 0; jj < 128; ++jj) {
        float hv = bf2f((unsigned short)hp0[(size_t)jj * D_]);
#pragma unroll
        for (int hh = 0; hh < 8; ++hh) acc[hh] += wl[hh][jj] * hv;
    }
#pragma unroll
    for (int hh = 0; hh < 8; ++hh)
        hp[((size_t)(jc * 32) + b * 8 + hh) * D_ + d] = acc[hh];
}

// ---------------------------------------------------------------------------
// Kernel 3: fused hp-reduce + ctx. 1024 blocks; block (bh, dg) reduces its
// (b,head) panel from hp into LDS (L2-resident) then computes 4 ctx outputs
// (one per wave) with coalesced Wr rows.
// ---------------------------------------------------------------------------
__global__ __launch_bounds__(256) void k_ctx(
    const float* __restrict__ hp, const float* __restrict__ Wr,
    float* __restrict__ ctx)
{
    const int bh = blockIdx.x >> 5;           // 0..31 = b*8 + head
    const int b = bh >> 3, head = bh & 7;
    const int dg = (blockIdx.x & 31) * 4;     // 4 outputs per block
    const int tid = threadIdx.x;
    const int lane = tid & 63, wave = tid >> 6;

    __shared__ float xs[1024];
    float4 s = {0.f, 0.f, 0.f, 0.f};
#pragma unroll
    for (int jc = 0; jc < 16; ++jc) {
        float4 v = ((const float4*)(hp + ((size_t)(jc * 32) + bh) * D_))[tid];
        s.x += v.x; s.y += v.y; s.z += v.z; s.w += v.w;
    }
    ((float4*)xs)[tid] = s;
    __syncthreads();

    const int o = dg + wave;                 // d' within head (0..127)
    const float* wrow = Wr + (size_t)(head * HD_ + o) * D_;
    float acc = 0.f;
#pragma unroll
    for (int it = 0; it < 4; ++it) {
        float4 wv = *(const float4*)(wrow + it * 256 + lane * 4);
        float4 xv = ((const float4*)xs)[it * 64 + lane];
        acc += wv.x * xv.x + wv.y * xv.y + wv.z * xv.z + wv.w * xv.w;
    }
#pragma unroll
    for (int m = 1; m < 64; m <<= 1) acc += __shfl_xor(acc, m);
    if (lane == 0) ctx[(size_t)b * D_ + head * HD_ + o] = acc;
}

// ---------------------------------------------------------------------------
// Kernel 4: fvec[b, o] = sum_e ctx[b,e] * Wf[o,e]  (1024 blocks)
// ---------------------------------------------------------------------------
__global__ __launch_bounds__(256) void k_fvec(
    const float* __restrict__ ctx, const float* __restrict__ Wf,
    float* __restrict__ fvec)
{
    const int o = blockIdx.x * 4 + (threadIdx.x >> 6);   // 0..4095
    const int lane = threadIdx.x & 63;
    const int b = o >> 10, orow = o & 1023;
    const float* x  = ctx + (size_t)b * D_;
    const float* wf = Wf + (size_t)orow * D_;
    float s = 0.f;
#pragma unroll
    for (int it = 0; it < 4; ++it) {
        float4 xv = *(const float4*)(x + it * 256 + lane * 4);
        float4 wv = *(const float4*)(wf + it * 256 + lane * 4);
        s += xv.x * wv.x + xv.y * wv.y + xv.z * wv.z + xv.w * wv.w;
    }
#pragma unroll
    for (int m = 1; m < 64; m <<= 1) s += __shfl_xor(s, m);
    if (lane == 0) fvec[o] = s;
}

// ---------------------------------------------------------------------------
// Kernel 5: out = LayerNorm(hb + fvec[b]) * gamma + beta, one block per row.
// Reads the bf16 copy of h (half the fetch; |err| <= 2^-9|h| ~ 0.008 vs
// threshold 0.1075).
// ---------------------------------------------------------------------------
__global__ __launch_bounds__(256) void k_ln(
    const short* __restrict__ hbm, const float* __restrict__ fvec,
    const float* __restrict__ gamma, const float* __restrict__ beta,
    float* __restrict__ out)
{
    const int row = blockIdx.x;
    const int b = row >> 11;
    const int tid = threadIdx.x;
    const int lane = tid & 63, wave = tid >> 6;

    short4 hv4 = *(const short4*)(hbm + (size_t)row * D_ + tid * 4);
    float4 fv = *(const float4*)(fvec + (size_t)b * D_ + tid * 4);
    const float y0 = bf2f((unsigned short)hv4.x) + fv.x;
    const float y1 = bf2f((unsigned short)hv4.y) + fv.y;
    const float y2 = bf2f((unsigned short)hv4.z) + fv.z;
    const float y3 = bf2f((unsigned short)hv4.w) + fv.w;

    float s = y0 + y1 + y2 + y3;
    float q = y0 * y0 + y1 * y1 + y2 * y2 + y3 * y3;
#pragma unroll
    for (int m = 1; m < 64; m <<= 1) { s += __shfl_xor(s, m); q += __shfl_xor(q, m); }

    __shared__ float rs[4], rq[4];
    if (lane == 0) { rs[wave] = s; rq[wave] = q; }
    __syncthreads();
    s = rs[0] + rs[1] + rs[2] + rs[3];
    q = rq[0] + rq[1] + rq[2] + rq[3];

    const float mu  = s * (1.f / D_);
    const float var = q * (1.f / D_) - mu * mu;
    const float inv = rsqrtf(var + 1e-5f);

    float4 gv = *(const float4*)(gamma + tid * 4);
    float4 bv = *(const float4*)(beta + tid * 4);
    float4 ov;
    ov.x = (y0 - mu) * inv * gv.x + bv.x;
    ov.y = (y1 - mu) * inv * gv.y + bv.y;
    ov.z = (y2 - mu) * inv * gv.z + bv.z;
    ov.w = (y3 - mu) * inv * gv.w + bv.w;
    *(float4*)(out + (size_t)row * D_ + tid * 4) = ov;
}

// ---------------------------------------------------------------------------
extern "C" void kernel_launch(void* const* d_in, const int* in_sizes, int n_in,
                              void* d_out, int out_size, void* d_ws, size_t ws_size,
                              hipStream_t stream) {
    const float* h     = (const float*)d_in[0];
    // d_in[1] = Wl  : dead (softmax over additive scores cancels sl)
    const float* Wr    = (const float*)d_in[2];
    // d_in[3] = att_l : dead
    const float* att_r = (const float*)d_in[4];
    const float* Wf    = (const float*)d_in[5];
    const float* gamma = (const float*)d_in[6];
    const float* beta  = (const float*)d_in[7];
    float* out = (float*)d_out;

    char* ws = (char*)d_ws;
    float* sr    = (float*)(ws);                  // B*H*N      = 256 KB
    float* hp    = (float*)(ws + 524288);         // 2 MB
    float* ctx   = (float*)(ws + 2752512);        // 16 KB
    float* fvec  = (float*)(ws + 2768896);        // 16 KB
    short* hb    = (short*)(ws + 4194304);        // 16 MB bf16 h
    short* wrb   = (short*)(ws + 4194304 + 16777216); // 2 MB bf16 Wr

    k_cvt<<<4096 + 512, 256, 0, stream>>>(h, hb, Wr, wrb);
    k_proj_sr<<<dim3(B_ * N_ / 64, H_), 256, 0, stream>>>(hb, wrb, att_r, sr);
    k_hbar<<<dim3(4, 16, 4), 256, 0, stream>>>(hb, sr, hp);
    k_ctx<<<1024, 256, 0, stream>>>(hp, Wr, ctx);
    k_fvec<<<1024, 256, 0, stream>>>(ctx, Wf, fvec);
    k_ln<<<B_ * N_, 256, 0, stream>>>(hb, fvec, gamma, beta, out);
}

// Round 19
// 73.994 us; speedup vs baseline: 1.0578x; 1.0578x over previous
//
#include <hip/hip_runtime.h>
#include <hip/hip_bf16.h>

#define B_ 4
#define N_ 2048
#define D_ 1024
#define H_ 8
#define HD_ 128

typedef __attribute__((ext_vector_type(4))) float f32x4;
typedef __attribute__((ext_vector_type(8))) short bf16x8;

__device__ __forceinline__ short f2bf(float f) {
    unsigned u = __builtin_bit_cast(unsigned, f);
    u = (u + 0x7FFFu + ((u >> 16) & 1u)) >> 16;   // round-to-nearest-even
    return (short)u;
}
__device__ __forceinline__ float bf2f(unsigned short s) {
    unsigned u = (unsigned)s << 16;
    return __builtin_bit_cast(float, u);
}

typedef const __attribute__((address_space(1))) void* gas_t;
typedef __attribute__((address_space(3))) void* las_t;

__device__ __forceinline__ void gload16(const void* g, void* l) {
    // lane i's 16B from per-lane g -> wave-uniform LDS base + lane*16
    __builtin_amdgcn_global_load_lds((gas_t)g, (las_t)l, 16, 0, 0);
}

// ---------------------------------------------------------------------------
// Kernel 0: fp32 -> bf16 pack for h (4096 blocks) and Wr (512 blocks), fused.
// ---------------------------------------------------------------------------
__global__ __launch_bounds__(256) void k_cvt(
    const float* __restrict__ h, short* __restrict__ hb,
    const float* __restrict__ Wr, short* __restrict__ wrb)
{
    int blk = blockIdx.x;
    const float* src;
    short* dst;
    int i;
    if (blk < 4096) { src = h;  dst = hb;  i = blk * 256 + threadIdx.x; }
    else            { src = Wr; dst = wrb; i = (blk - 4096) * 256 + threadIdx.x; }
    float4 a = ((const float4*)src)[i * 2];
    float4 b = ((const float4*)src)[i * 2 + 1];
    bf16x8 o;
    o[0] = f2bf(a.x); o[1] = f2bf(a.y); o[2] = f2bf(a.z); o[3] = f2bf(a.w);
    o[4] = f2bf(b.x); o[5] = f2bf(b.y); o[6] = f2bf(b.z); o[7] = f2bf(b.w);
    ((bf16x8*)dst)[i] = o;
}

// ---------------------------------------------------------------------------
// Kernel 1: GEMM fr = h @ Wr^T, 128x128 tile, BK=32, single buffer, 2
// barriers/step, linear LDS, 4 waves (2x2 of 64x64, 4x4 frags). 512 blocks.
// Rationale: pipelining variants (dbuf+syncthreads R17, counted-vmcnt R18)
// were all NEUTRAL -> proj is NOT drain-stalled; remaining lever is LDS
// traffic per MFMA: this tile reads 500B/MFMA vs 64x128's 750B/MFMA
// (1.5x less LDS pressure per unit work). Single-variable test vs R18.
// Fused epilogue: sr[b,head,j] = sum_c leaky(fr[j, head*128+c]) * att_r[c]
// ---------------------------------------------------------------------------
__global__ __launch_bounds__(256) void k_proj_sr(
    const short* __restrict__ hb, const short* __restrict__ wrb,
    const float* __restrict__ att_r, float* __restrict__ sr)
{
    __shared__ short sA[128 * 32];     // 8 KB, row-major [128][32]
    __shared__ short sB[128 * 32];     // 8 KB
    __shared__ float part[2][128];

    const int tid  = threadIdx.x;
    const int lane = tid & 63;
    const int wave = tid >> 6;
    const int cc   = lane & 15;
    const int g    = lane >> 4;
    const int wr   = wave >> 1;        // wave row (0..1)
    const int wc   = wave & 1;         // wave col (0..1)
    const int rowBase = blockIdx.x * 128;   // global j-row base (0..8191)
    const int head    = blockIdx.y;

    // staging geometry: wave covers LDS bytes [(wave*2+q)*1024, +1024)
    const int r0q0 = (wave * 2) * 16 + (lane >> 2);   // row_local for q=0
    const int colb = (lane & 3) * 8;                  // k-offset (bf16 elems)
    const short* gA0 = hb  + (size_t)(rowBase + r0q0) * D_ + colb;
    const short* gB0 = wrb + (size_t)(head * HD_ + r0q0) * D_ + colb;
    char* lA = (char*)sA + (size_t)(wave * 2) * 1024;
    char* lB = (char*)sB + (size_t)(wave * 2) * 1024;

    f32x4 acc[4][4];
#pragma unroll
    for (int m = 0; m < 4; ++m)
#pragma unroll
        for (int n = 0; n < 4; ++n) acc[m][n] = (f32x4){0.f, 0.f, 0.f, 0.f};

    for (int k0 = 0; k0 < D_; k0 += 32) {
        // stage A,B tiles (each wave: 2+2 issues of 1024B)
        gload16(gA0 + k0,            lA);
        gload16(gA0 + k0 + 16 * D_,  lA + 1024);
        gload16(gB0 + k0,            lB);
        gload16(gB0 + k0 + 16 * D_,  lB + 1024);
        __syncthreads();   // drains vmcnt(0) before barrier

        bf16x8 aF[4], bF[4];
#pragma unroll
        for (int m = 0; m < 4; ++m)
            aF[m] = *(const bf16x8*)(sA + ((wr * 64 + m * 16 + cc) * 32 + g * 8));
#pragma unroll
        for (int n = 0; n < 4; ++n)
            bF[n] = *(const bf16x8*)(sB + ((wc * 64 + n * 16 + cc) * 32 + g * 8));
#pragma unroll
        for (int m = 0; m < 4; ++m)
#pragma unroll
            for (int n = 0; n < 4; ++n)
                acc[m][n] = __builtin_amdgcn_mfma_f32_16x16x32_bf16(
                    aF[m], bF[n], acc[m][n], 0, 0, 0);
        __syncthreads();   // protect LDS before next stage
    }

    // Epilogue: row = rowBase + wr*64 + m*16 + g*4 + reg,
    //           col_in_head = wc*64 + n*16 + cc
    float ar[4];
#pragma unroll
    for (int n = 0; n < 4; ++n) ar[n] = att_r[wc * 64 + n * 16 + cc];

#pragma unroll
    for (int m = 0; m < 4; ++m) {
#pragma unroll
        for (int r = 0; r < 4; ++r) {
            float p = 0.f;
#pragma unroll
            for (int n = 0; n < 4; ++n) {
                float v = acc[m][n][r];
                v = v > 0.f ? v : 0.01f * v;    // leaky
                p += v * ar[n];
            }
            p += __shfl_xor(p, 1); p += __shfl_xor(p, 2);
            p += __shfl_xor(p, 4); p += __shfl_xor(p, 8);
            if (cc == 0) part[wc][wr * 64 + m * 16 + g * 4 + r] = p;
        }
    }
    __syncthreads();
    if (tid < 128) {
        const int grow = rowBase + tid;
        const int b = grow >> 11, j = grow & (N_ - 1);
        sr[(size_t)(b * H_ + head) * N_ + j] = part[0][tid] + part[1][tid];
    }
}

// ---------------------------------------------------------------------------
// Kernel 2: hbar partials with inline softmax stats (L2-resident sr).
//   hp[jc*32 + b*8 + h][d] = sum_{j in chunk jc} exp(sr-mx)/sum * hb[b,j,d]
// Grid dim3(4 dc, 16 jc, 4 b) = 256 blocks.
// ---------------------------------------------------------------------------
__global__ __launch_bounds__(256) void k_hbar(
    const short* __restrict__ hbm, const float* __restrict__ sr,
    float* __restrict__ hp)
{
    const int dc = blockIdx.x;   // 0..3
    const int jc = blockIdx.y;   // 0..15  (128 j each)
    const int b  = blockIdx.z;   // 0..3
    const int tid = threadIdx.x;
    const int d = dc * 256 + tid;

    __shared__ float smx[8], sism[8];
    {
        const int hh = tid >> 5;
        const int sl = tid & 31;
        const float4* row = (const float4*)(sr + (size_t)(b * H_ + hh) * N_);
        float4 v[16];
        float mx = -1e30f;
#pragma unroll
        for (int k = 0; k < 16; ++k) {
            v[k] = row[sl + k * 32];
            mx = fmaxf(fmaxf(mx, fmaxf(v[k].x, v[k].y)), fmaxf(v[k].z, v[k].w));
        }
#pragma unroll
        for (int m = 1; m < 32; m <<= 1) mx = fmaxf(mx, __shfl_xor(mx, m));
        float sum = 0.f;
#pragma unroll
        for (int k = 0; k < 16; ++k)
            sum += expf(v[k].x - mx) + expf(v[k].y - mx) +
                   expf(v[k].z - mx) + expf(v[k].w - mx);
#pragma unroll
        for (int m = 1; m < 32; m <<= 1) sum += __shfl_xor(sum, m);
        if (sl == 0) { smx[hh] = mx; sism[hh] = 1.f / sum; }
    }
    __syncthreads();

    __shared__ float wl[8][128];
    for (int idx = tid; idx < 1024; idx += 256) {
        const int hh = idx >> 7, jj = idx & 127;
        wl[hh][jj] = expf(sr[(size_t)(b * H_ + hh) * N_ + jc * 128 + jj]
                          - smx[hh]) * sism[hh];
    }
    __syncthreads();

    float acc[8] = {0.f, 0.f, 0.f, 0.f, 0.f, 0.f, 0.f, 0.f};
    const short* hp0 = hbm + ((size_t)(b * N_ + jc * 128)) * D_ + d;
#pragma unroll 4
    for (int jj = 0; jj < 128; ++jj) {
        float hv = bf2f((unsigned short)hp0[(size_t)jj * D_]);
#pragma unroll
        for (int hh = 0; hh < 8; ++hh) acc[hh] += wl[hh][jj] * hv;
    }
#pragma unroll
    for (int hh = 0; hh < 8; ++hh)
        hp[((size_t)(jc * 32) + b * 8 + hh) * D_ + d] = acc[hh];
}

// ---------------------------------------------------------------------------
// Kernel 3: fused hp-reduce + ctx. 1024 blocks; block (bh, dg) reduces its
// (b,head) panel from hp into LDS (L2-resident) then computes 4 ctx outputs
// (one per wave) with coalesced Wr rows.
// ---------------------------------------------------------------------------
__global__ __launch_bounds__(256) void k_ctx(
    const float* __restrict__ hp, const float* __restrict__ Wr,
    float* __restrict__ ctx)
{
    const int bh = blockIdx.x >> 5;           // 0..31 = b*8 + head
    const int b = bh >> 3, head = bh & 7;
    const int dg = (blockIdx.x & 31) * 4;     // 4 outputs per block
    const int tid = threadIdx.x;
    const int lane = tid & 63, wave = tid >> 6;

    __shared__ float xs[1024];
    float4 s = {0.f, 0.f, 0.f, 0.f};
#pragma unroll
    for (int jc = 0; jc < 16; ++jc) {
        float4 v = ((const float4*)(hp + ((size_t)(jc * 32) + bh) * D_))[tid];
        s.x += v.x; s.y += v.y; s.z += v.z; s.w += v.w;
    }
    ((float4*)xs)[tid] = s;
    __syncthreads();

    const int o = dg + wave;                 // d' within head (0..127)
    const float* wrow = Wr + (size_t)(head * HD_ + o) * D_;
    float acc = 0.f;
#pragma unroll
    for (int it = 0; it < 4; ++it) {
        float4 wv = *(const float4*)(wrow + it * 256 + lane * 4);
        float4 xv = ((const float4*)xs)[it * 64 + lane];
        acc += wv.x * xv.x + wv.y * xv.y + wv.z * xv.z + wv.w * xv.w;
    }
#pragma unroll
    for (int m = 1; m < 64; m <<= 1) acc += __shfl_xor(acc, m);
    if (lane == 0) ctx[(size_t)b * D_ + head * HD_ + o] = acc;
}

// ---------------------------------------------------------------------------
// Kernel 4: fvec[b, o] = sum_e ctx[b,e] * Wf[o,e]  (1024 blocks)
// ---------------------------------------------------------------------------
__global__ __launch_bounds__(256) void k_fvec(
    const float* __restrict__ ctx, const float* __restrict__ Wf,
    float* __restrict__ fvec)
{
    const int o = blockIdx.x * 4 + (threadIdx.x >> 6);   // 0..4095
    const int lane = threadIdx.x & 63;
    const int b = o >> 10, orow = o & 1023;
    const float* x  = ctx + (size_t)b * D_;
    const float* wf = Wf + (size_t)orow * D_;
    float s = 0.f;
#pragma unroll
    for (int it = 0; it < 4; ++it) {
        float4 xv = *(const float4*)(x + it * 256 + lane * 4);
        float4 wv = *(const float4*)(wf + it * 256 + lane * 4);
        s += xv.x * wv.x + xv.y * wv.y + xv.z * wv.z + xv.w * wv.w;
    }
#pragma unroll
    for (int m = 1; m < 64; m <<= 1) s += __shfl_xor(s, m);
    if (lane == 0) fvec[o] = s;
}

// ---------------------------------------------------------------------------
// Kernel 5: out = LayerNorm(hb + fvec[b]) * gamma + beta, one block per row.
// Reads the bf16 copy of h (half the fetch; |err| <= 2^-9|h| ~ 0.008 vs
// threshold 0.1075).
// ---------------------------------------------------------------------------
__global__ __launch_bounds__(256) void k_ln(
    const short* __restrict__ hbm, const float* __restrict__ fvec,
    const float* __restrict__ gamma, const float* __restrict__ beta,
    float* __restrict__ out)
{
    const int row = blockIdx.x;
    const int b = row >> 11;
    const int tid = threadIdx.x;
    const int lane = tid & 63, wave = tid >> 6;

    short4 hv4 = *(const short4*)(hbm + (size_t)row * D_ + tid * 4);
    float4 fv = *(const float4*)(fvec + (size_t)b * D_ + tid * 4);
    const float y0 = bf2f((unsigned short)hv4.x) + fv.x;
    const float y1 = bf2f((unsigned short)hv4.y) + fv.y;
    const float y2 = bf2f((unsigned short)hv4.z) + fv.z;
    const float y3 = bf2f((unsigned short)hv4.w) + fv.w;

    float s = y0 + y1 + y2 + y3;
    float q = y0 * y0 + y1 * y1 + y2 * y2 + y3 * y3;
#pragma unroll
    for (int m = 1; m < 64; m <<= 1) { s += __shfl_xor(s, m); q += __shfl_xor(q, m); }

    __shared__ float rs[4], rq[4];
    if (lane == 0) { rs[wave] = s; rq[wave] = q; }
    __syncthreads();
    s = rs[0] + rs[1] + rs[2] + rs[3];
    q = rq[0] + rq[1] + rq[2] + rq[3];

    const float mu  = s * (1.f / D_);
    const float var = q * (1.f / D_) - mu * mu;
    const float inv = rsqrtf(var + 1e-5f);

    float4 gv = *(const float4*)(gamma + tid * 4);
    float4 bv = *(const float4*)(beta + tid * 4);
    float4 ov;
    ov.x = (y0 - mu) * inv * gv.x + bv.x;
    ov.y = (y1 - mu) * inv * gv.y + bv.y;
    ov.z = (y2 - mu) * inv * gv.z + bv.z;
    ov.w = (y3 - mu) * inv * gv.w + bv.w;
    *(float4*)(out + (size_t)row * D_ + tid * 4) = ov;
}

// ---------------------------------------------------------------------------
extern "C" void kernel_launch(void* const* d_in, const int* in_sizes, int n_in,
                              void* d_out, int out_size, void* d_ws, size_t ws_size,
                              hipStream_t stream) {
    const float* h     = (const float*)d_in[0];
    // d_in[1] = Wl  : dead (softmax over additive scores cancels sl)
    const float* Wr    = (const float*)d_in[2];
    // d_in[3] = att_l : dead
    const float* att_r = (const float*)d_in[4];
    const float* Wf    = (const float*)d_in[5];
    const float* gamma = (const float*)d_in[6];
    const float* beta  = (const float*)d_in[7];
    float* out = (float*)d_out;

    char* ws = (char*)d_ws;
    float* sr    = (float*)(ws);                  // B*H*N      = 256 KB
    float* hp    = (float*)(ws + 524288);         // 2 MB
    float* ctx   = (float*)(ws + 2752512);        // 16 KB
    float* fvec  = (float*)(ws + 2768896);        // 16 KB
    short* hb    = (short*)(ws + 4194304);        // 16 MB bf16 h
    short* wrb   = (short*)(ws + 4194304 + 16777216); // 2 MB bf16 Wr

    k_cvt<<<4096 + 512, 256, 0, stream>>>(h, hb, Wr, wrb);
    k_proj_sr<<<dim3(B_ * N_ / 128, H_), 256, 0, stream>>>(hb, wrb, att_r, sr);
    k_hbar<<<dim3(4, 16, 4), 256, 0, stream>>>(hb, sr, hp);
    k_ctx<<<1024, 256, 0, stream>>>(hp, Wr, ctx);
    k_fvec<<<1024, 256, 0, stream>>>(ctx, Wf, fvec);
    k_ln<<<B_ * N_, 256, 0, stream>>>(hb, fvec, gamma, beta, out);
}

// Round 20
// 69.710 us; speedup vs baseline: 1.1228x; 1.0615x over previous
//
#include <hip/hip_runtime.h>
#include <hip/hip_bf16.h>

#define B_ 4
#define N_ 2048
#define D_ 1024
#define H_ 8
#define HD_ 128

typedef __attribute__((ext_vector_type(4))) float f32x4;
typedef __attribute__((ext_vector_type(8))) short bf16x8;

__device__ __forceinline__ short f2bf(float f) {
    unsigned u = __builtin_bit_cast(unsigned, f);
    u = (u + 0x7FFFu + ((u >> 16) & 1u)) >> 16;   // round-to-nearest-even
    return (short)u;
}
__device__ __forceinline__ float bf2f(unsigned short s) {
    unsigned u = (unsigned)s << 16;
    return __builtin_bit_cast(float, u);
}

typedef const __attribute__((address_space(1))) void* gas_t;
typedef __attribute__((address_space(3))) void* las_t;

__device__ __forceinline__ void gload16(const void* g, void* l) {
    // lane i's 16B from per-lane g -> wave-uniform LDS base + lane*16
    __builtin_amdgcn_global_load_lds((gas_t)g, (las_t)l, 16, 0, 0);
}

// ---------------------------------------------------------------------------
// Kernel 0: fp32 -> bf16 pack for h (4096 blocks) and Wr (512 blocks), fused.
// ---------------------------------------------------------------------------
__global__ __launch_bounds__(256) void k_cvt(
    const float* __restrict__ h, short* __restrict__ hb,
    const float* __restrict__ Wr, short* __restrict__ wrb)
{
    int blk = blockIdx.x;
    const float* src;
    short* dst;
    int i;
    if (blk < 4096) { src = h;  dst = hb;  i = blk * 256 + threadIdx.x; }
    else            { src = Wr; dst = wrb; i = (blk - 4096) * 256 + threadIdx.x; }
    float4 a = ((const float4*)src)[i * 2];
    float4 b = ((const float4*)src)[i * 2 + 1];
    bf16x8 o;
    o[0] = f2bf(a.x); o[1] = f2bf(a.y); o[2] = f2bf(a.z); o[3] = f2bf(a.w);
    o[4] = f2bf(b.x); o[5] = f2bf(b.y); o[6] = f2bf(b.z); o[7] = f2bf(b.w);
    ((bf16x8*)dst)[i] = o;
}

// ---------------------------------------------------------------------------
// Kernel 1: GEMM fr = h @ Wr^T, 128x128 tile, BK=64 (32 barriers vs R19's
// 64 -- pipelining probes were all neutral so the remaining proj tax scales
// with barrier count, not drain latency), single buffer, 2 barriers/step,
// 4 waves (2x2 of 64x64, 4x4 frags), 512 blocks, identity grid.
// BK=64 rows are 128B-stride (16-way bank conflict) -> both-sides XOR
// swizzle (rule #21): stored slot = src_slot ^ (row&7) via pre-swizzled
// GLOBAL source col; read slot = (kk*4+g) ^ (cc&7)  => ~2-way (free).
// This is R3's proj minus R3's L2-thrashing head-chunk grid swizzle.
// Fused epilogue: sr[b,head,j] = sum_c leaky(fr[j, head*128+c]) * att_r[c]
// ---------------------------------------------------------------------------
__global__ __launch_bounds__(256) void k_proj_sr(
    const short* __restrict__ hb, const short* __restrict__ wrb,
    const float* __restrict__ att_r, float* __restrict__ sr)
{
    __shared__ short sA[128 * 64];     // 16 KB, [row][slot^(row&7)] (16B slots)
    __shared__ short sB[128 * 64];     // 16 KB
    __shared__ float part[2][128];

    const int tid  = threadIdx.x;
    const int lane = tid & 63;
    const int wave = tid >> 6;
    const int cc   = lane & 15;
    const int g    = lane >> 4;
    const int wr   = wave >> 1;        // wave row (0..1)
    const int wc   = wave & 1;         // wave col (0..1)
    const int rowBase = blockIdx.x * 128;
    const int head    = blockIdx.y;

    // staging: wave stages rows [wave*32,+32) of A and of B, 4 issues each
    // (8 rows x 128B per issue). Lane l -> row srow=l>>3, 16B-slot (l&7);
    // source slot XOR'd with (srow) so the linear LDS write realizes the
    // swizzled layout.
    const int srow = lane >> 3;                       // 0..7
    const int scol = ((lane & 7) ^ srow) * 8;         // bf16 elems
    const short* gA0 = hb  + (size_t)(rowBase + wave * 32 + srow) * D_ + scol;
    const short* gB0 = wrb + (size_t)(head * HD_ + wave * 32 + srow) * D_ + scol;
    char* lA = (char*)sA + wave * 32 * 128;           // bytes
    char* lB = (char*)sB + wave * 32 * 128;

    f32x4 acc[4][4];
#pragma unroll
    for (int m = 0; m < 4; ++m)
#pragma unroll
        for (int n = 0; n < 4; ++n) acc[m][n] = (f32x4){0.f, 0.f, 0.f, 0.f};

    for (int k0 = 0; k0 < D_; k0 += 64) {
#pragma unroll
        for (int q = 0; q < 4; ++q) {
            gload16(gA0 + k0 + q * 8 * D_, lA + q * 1024);
            gload16(gB0 + k0 + q * 8 * D_, lB + q * 1024);
        }
        __syncthreads();   // drains vmcnt(0) before barrier

#pragma unroll
        for (int kk = 0; kk < 2; ++kk) {
            bf16x8 aF[4], bF[4];
#pragma unroll
            for (int m = 0; m < 4; ++m) {
                const int row = wr * 64 + m * 16 + cc;
                const int ks  = (kk * 64 + g * 16) ^ ((cc & 7) << 4);
                aF[m] = *(const bf16x8*)((const char*)sA + row * 128 + ks);
            }
#pragma unroll
            for (int n = 0; n < 4; ++n) {
                const int row = wc * 64 + n * 16 + cc;
                const int ks  = (kk * 64 + g * 16) ^ ((cc & 7) << 4);
                bF[n] = *(const bf16x8*)((const char*)sB + row * 128 + ks);
            }
#pragma unroll
            for (int m = 0; m < 4; ++m)
#pragma unroll
                for (int n = 0; n < 4; ++n)
                    acc[m][n] = __builtin_amdgcn_mfma_f32_16x16x32_bf16(
                        aF[m], bF[n], acc[m][n], 0, 0, 0);
        }
        __syncthreads();   // protect LDS before next stage
    }

    // Epilogue: row = rowBase + wr*64 + m*16 + g*4 + reg,
    //           col_in_head = wc*64 + n*16 + cc
    float ar[4];
#pragma unroll
    for (int n = 0; n < 4; ++n) ar[n] = att_r[wc * 64 + n * 16 + cc];

#pragma unroll
    for (int m = 0; m < 4; ++m) {
#pragma unroll
        for (int r = 0; r < 4; ++r) {
            float p = 0.f;
#pragma unroll
            for (int n = 0; n < 4; ++n) {
                float v = acc[m][n][r];
                v = v > 0.f ? v : 0.01f * v;    // leaky
                p += v * ar[n];
            }
            p += __shfl_xor(p, 1); p += __shfl_xor(p, 2);
            p += __shfl_xor(p, 4); p += __shfl_xor(p, 8);
            if (cc == 0) part[wc][wr * 64 + m * 16 + g * 4 + r] = p;
        }
    }
    __syncthreads();
    if (tid < 128) {
        const int grow = rowBase + tid;
        const int b = grow >> 11, j = grow & (N_ - 1);
        sr[(size_t)(b * H_ + head) * N_ + j] = part[0][tid] + part[1][tid];
    }
}

// ---------------------------------------------------------------------------
// Kernel 2: hbar partials with inline softmax stats (L2-resident sr).
//   hp[jc*32 + b*8 + h][d] = sum_{j in chunk jc} exp(sr-mx)/sum * hb[b,j,d]
// Grid dim3(4 dc, 16 jc, 4 b) = 256 blocks.
// ---------------------------------------------------------------------------
__global__ __launch_bounds__(256) void k_hbar(
    const short* __restrict__ hbm, const float* __restrict__ sr,
    float* __restrict__ hp)
{
    const int dc = blockIdx.x;   // 0..3
    const int jc = blockIdx.y;   // 0..15  (128 j each)
    const int b  = blockIdx.z;   // 0..3
    const int tid = threadIdx.x;
    const int d = dc * 256 + tid;

    __shared__ float smx[8], sism[8];
    {
        const int hh = tid >> 5;
        const int sl = tid & 31;
        const float4* row = (const float4*)(sr + (size_t)(b * H_ + hh) * N_);
        float4 v[16];
        float mx = -1e30f;
#pragma unroll
        for (int k = 0; k < 16; ++k) {
            v[k] = row[sl + k * 32];
            mx = fmaxf(fmaxf(mx, fmaxf(v[k].x, v[k].y)), fmaxf(v[k].z, v[k].w));
        }
#pragma unroll
        for (int m = 1; m < 32; m <<= 1) mx = fmaxf(mx, __shfl_xor(mx, m));
        float sum = 0.f;
#pragma unroll
        for (int k = 0; k < 16; ++k)
            sum += expf(v[k].x - mx) + expf(v[k].y - mx) +
                   expf(v[k].z - mx) + expf(v[k].w - mx);
#pragma unroll
        for (int m = 1; m < 32; m <<= 1) sum += __shfl_xor(sum, m);
        if (sl == 0) { smx[hh] = mx; sism[hh] = 1.f / sum; }
    }
    __syncthreads();

    __shared__ float wl[8][128];
    for (int idx = tid; idx < 1024; idx += 256) {
        const int hh = idx >> 7, jj = idx & 127;
        wl[hh][jj] = expf(sr[(size_t)(b * H_ + hh) * N_ + jc * 128 + jj]
                          - smx[hh]) * sism[hh];
    }
    __syncthreads();

    float acc[8] = {0.f, 0.f, 0.f, 0.f, 0.f, 0.f, 0.f, 0.f};
    const short* hp0 = hbm + ((size_t)(b * N_ + jc * 128)) * D_ + d;
#pragma unroll 4
    for (int jj = 0; jj < 128; ++jj) {
        float hv = bf2f((unsigned short)hp0[(size_t)jj * D_]);
#pragma unroll
        for (int hh = 0; hh < 8; ++hh) acc[hh] += wl[hh][jj] * hv;
    }
#pragma unroll
    for (int hh = 0; hh < 8; ++hh)
        hp[((size_t)(jc * 32) + b * 8 + hh) * D_ + d] = acc[hh];
}

// ---------------------------------------------------------------------------
// Kernel 3: fused hp-reduce + ctx. 1024 blocks; block (bh, dg) reduces its
// (b,head) panel from hp into LDS (L2-resident) then computes 4 ctx outputs
// (one per wave) with coalesced Wr rows.
// ---------------------------------------------------------------------------
__global__ __launch_bounds__(256) void k_ctx(
    const float* __restrict__ hp, const float* __restrict__ Wr,
    float* __restrict__ ctx)
{
    const int bh = blockIdx.x >> 5;           // 0..31 = b*8 + head
    const int b = bh >> 3, head = bh & 7;
    const int dg = (blockIdx.x & 31) * 4;     // 4 outputs per block
    const int tid = threadIdx.x;
    const int lane = tid & 63, wave = tid >> 6;

    __shared__ float xs[1024];
    float4 s = {0.f, 0.f, 0.f, 0.f};
#pragma unroll
    for (int jc = 0; jc < 16; ++jc) {
        float4 v = ((const float4*)(hp + ((size_t)(jc * 32) + bh) * D_))[tid];
        s.x += v.x; s.y += v.y; s.z += v.z; s.w += v.w;
    }
    ((float4*)xs)[tid] = s;
    __syncthreads();

    const int o = dg + wave;                 // d' within head (0..127)
    const float* wrow = Wr + (size_t)(head * HD_ + o) * D_;
    float acc = 0.f;
#pragma unroll
    for (int it = 0; it < 4; ++it) {
        float4 wv = *(const float4*)(wrow + it * 256 + lane * 4);
        float4 xv = ((const float4*)xs)[it * 64 + lane];
        acc += wv.x * xv.x + wv.y * xv.y + wv.z * xv.z + wv.w * xv.w;
    }
#pragma unroll
    for (int m = 1; m < 64; m <<= 1) acc += __shfl_xor(acc, m);
    if (lane == 0) ctx[(size_t)b * D_ + head * HD_ + o] = acc;
}

// ---------------------------------------------------------------------------
// Kernel 4: fvec[b, o] = sum_e ctx[b,e] * Wf[o,e]  (1024 blocks)
// ---------------------------------------------------------------------------
__global__ __launch_bounds__(256) void k_fvec(
    const float* __restrict__ ctx, const float* __restrict__ Wf,
    float* __restrict__ fvec)
{
    const int o = blockIdx.x * 4 + (threadIdx.x >> 6);   // 0..4095
    const int lane = threadIdx.x & 63;
    const int b = o >> 10, orow = o & 1023;
    const float* x  = ctx + (size_t)b * D_;
    const float* wf = Wf + (size_t)orow * D_;
    float s = 0.f;
#pragma unroll
    for (int it = 0; it < 4; ++it) {
        float4 xv = *(const float4*)(x + it * 256 + lane * 4);
        float4 wv = *(const float4*)(wf + it * 256 + lane * 4);
        s += xv.x * wv.x + xv.y * wv.y + xv.z * wv.z + xv.w * wv.w;
    }
#pragma unroll
    for (int m = 1; m < 64; m <<= 1) s += __shfl_xor(s, m);
    if (lane == 0) fvec[o] = s;
}

// ---------------------------------------------------------------------------
// Kernel 5: out = LayerNorm(hb + fvec[b]) * gamma + beta, one block per row.
// Reads the bf16 copy of h (half the fetch; |err| <= 2^-9|h| ~ 0.008 vs
// threshold 0.1075).
// ---------------------------------------------------------------------------
__global__ __launch_bounds__(256) void k_ln(
    const short* __restrict__ hbm, const float* __restrict__ fvec,
    const float* __restrict__ gamma, const float* __restrict__ beta,
    float* __restrict__ out)
{
    const int row = blockIdx.x;
    const int b = row >> 11;
    const int tid = threadIdx.x;
    const int lane = tid & 63, wave = tid >> 6;

    short4 hv4 = *(const short4*)(hbm + (size_t)row * D_ + tid * 4);
    float4 fv = *(const float4*)(fvec + (size_t)b * D_ + tid * 4);
    const float y0 = bf2f((unsigned short)hv4.x) + fv.x;
    const float y1 = bf2f((unsigned short)hv4.y) + fv.y;
    const float y2 = bf2f((unsigned short)hv4.z) + fv.z;
    const float y3 = bf2f((unsigned short)hv4.w) + fv.w;

    float s = y0 + y1 + y2 + y3;
    float q = y0 * y0 + y1 * y1 + y2 * y2 + y3 * y3;
#pragma unroll
    for (int m = 1; m < 64; m <<= 1) { s += __shfl_xor(s, m); q += __shfl_xor(q, m); }

    __shared__ float rs[4], rq[4];
    if (lane == 0) { rs[wave] = s; rq[wave] = q; }
    __syncthreads();
    s = rs[0] + rs[1] + rs[2] + rs[3];
    q = rq[0] + rq[1] + rq[2] + rq[3];

    const float mu  = s * (1.f / D_);
    const float var = q * (1.f / D_) - mu * mu;
    const float inv = rsqrtf(var + 1e-5f);

    float4 gv = *(const float4*)(gamma + tid * 4);
    float4 bv = *(const float4*)(beta + tid * 4);
    float4 ov;
    ov.x = (y0 - mu) * inv * gv.x + bv.x;
    ov.y = (y1 - mu) * inv * gv.y + bv.y;
    ov.z = (y2 - mu) * inv * gv.z + bv.z;
    ov.w = (y3 - mu) * inv * gv.w + bv.w;
    *(float4*)(out + (size_t)row * D_ + tid * 4) = ov;
}

// ---------------------------------------------------------------------------
extern "C" void kernel_launch(void* const* d_in, const int* in_sizes, int n_in,
                              void* d_out, int out_size, void* d_ws, size_t ws_size,
                              hipStream_t stream) {
    const float* h     = (const float*)d_in[0];
    // d_in[1] = Wl  : dead (softmax over additive scores cancels sl)
    const float* Wr    = (const float*)d_in[2];
    // d_in[3] = att_l : dead
    const float* att_r = (const float*)d_in[4];
    const float* Wf    = (const float*)d_in[5];
    const float* gamma = (const float*)d_in[6];
    const float* beta  = (const float*)d_in[7];
    float* out = (float*)d_out;

    char* ws = (char*)d_ws;
    float* sr    = (float*)(ws);                  // B*H*N      = 256 KB
    float* hp    = (float*)(ws + 524288);         // 2 MB
    float* ctx   = (float*)(ws + 2752512);        // 16 KB
    float* fvec  = (float*)(ws + 2768896);        // 16 KB
    short* hb    = (short*)(ws + 4194304);        // 16 MB bf16 h
    short* wrb   = (short*)(ws + 4194304 + 16777216); // 2 MB bf16 Wr

    k_cvt<<<4096 + 512, 256, 0, stream>>>(h, hb, Wr, wrb);
    k_proj_sr<<<dim3(B_ * N_ / 128, H_), 256, 0, stream>>>(hb, wrb, att_r, sr);
    k_hbar<<<dim3(4, 16, 4), 256, 0, stream>>>(hb, sr, hp);
    k_ctx<<<1024, 256, 0, stream>>>(hp, Wr, ctx);
    k_fvec<<<1024, 256, 0, stream>>>(ctx, Wf, fvec);
    k_ln<<<B_ * N_, 256, 0, stream>>>(hb, fvec, gamma, beta, out);
}

// Round 21
// 69.488 us; speedup vs baseline: 1.1264x; 1.0032x over previous
//
#include <hip/hip_runtime.h>
#include <hip/hip_bf16.h>

#define B_ 4
#define N_ 2048
#define D_ 1024
#define H_ 8
#define HD_ 128

typedef __attribute__((ext_vector_type(4))) float f32x4;
typedef __attribute__((ext_vector_type(8))) short bf16x8;

__device__ __forceinline__ short f2bf(float f) {
    unsigned u = __builtin_bit_cast(unsigned, f);
    u = (u + 0x7FFFu + ((u >> 16) & 1u)) >> 16;   // round-to-nearest-even
    return (short)u;
}
__device__ __forceinline__ float bf2f(unsigned short s) {
    unsigned u = (unsigned)s << 16;
    return __builtin_bit_cast(float, u);
}

typedef const __attribute__((address_space(1))) void* gas_t;
typedef __attribute__((address_space(3))) void* las_t;

__device__ __forceinline__ void gload16(const void* g, void* l) {
    // lane i's 16B from per-lane g -> wave-uniform LDS base + lane*16
    __builtin_amdgcn_global_load_lds((gas_t)g, (las_t)l, 16, 0, 0);
}

// ---------------------------------------------------------------------------
// Kernel 0: fp32 -> bf16 pack for h (4096 blocks) and Wr (512 blocks), fused.
// ---------------------------------------------------------------------------
__global__ __launch_bounds__(256) void k_cvt(
    const float* __restrict__ h, short* __restrict__ hb,
    const float* __restrict__ Wr, short* __restrict__ wrb)
{
    int blk = blockIdx.x;
    const float* src;
    short* dst;
    int i;
    if (blk < 4096) { src = h;  dst = hb;  i = blk * 256 + threadIdx.x; }
    else            { src = Wr; dst = wrb; i = (blk - 4096) * 256 + threadIdx.x; }
    float4 a = ((const float4*)src)[i * 2];
    float4 b = ((const float4*)src)[i * 2 + 1];
    bf16x8 o;
    o[0] = f2bf(a.x); o[1] = f2bf(a.y); o[2] = f2bf(a.z); o[3] = f2bf(a.w);
    o[4] = f2bf(b.x); o[5] = f2bf(b.y); o[6] = f2bf(b.z); o[7] = f2bf(b.w);
    ((bf16x8*)dst)[i] = o;
}

// ---------------------------------------------------------------------------
// Kernel 1: GEMM fr = h @ Wr^T, 128x128 tile, BK=128 -> 16 barriers total.
// Barrier-count lever twice-confirmed (BK 32->64: -4.3us). m132's BK=128
// regression was occupancy 3->2 blocks/CU; here LDS 64KB keeps 2/CU (already
// the cap at 512 blocks) so that failure mode doesn't apply.
// Swizzle (rule #21, 16-slot): stored[row][s] = src[row][s^(row&15)] via
// pre-swizzled GLOBAL source; read slot = (kk*4+g)^(row&15), row&15 == cc
// => 16 distinct slots per 16-lane group => 2-way bank alias (free).
// 4 waves (2x2 of 64x64, 4x4 frags), 512 blocks, identity grid.
// Fused epilogue: sr[b,head,j] = sum_c leaky(fr[j, head*128+c]) * att_r[c]
// ---------------------------------------------------------------------------
__global__ __launch_bounds__(256) void k_proj_sr(
    const short* __restrict__ hb, const short* __restrict__ wrb,
    const float* __restrict__ att_r, float* __restrict__ sr)
{
    __shared__ short sA[128 * 128];    // 32 KB, [row][slot^(row&15)] 16B slots
    __shared__ short sB[128 * 128];    // 32 KB
    __shared__ float part[2][128];

    const int tid  = threadIdx.x;
    const int lane = tid & 63;
    const int wave = tid >> 6;
    const int cc   = lane & 15;
    const int g    = lane >> 4;
    const int wr   = wave >> 1;        // wave row (0..1)
    const int wc   = wave & 1;         // wave col (0..1)
    const int rowBase = blockIdx.x * 128;
    const int head    = blockIdx.y;

    // staging: wave stages rows [wave*32,+32) of A and B; 8 issues each of
    // 1024B = 4 rows x 256B. lane l -> row_in_issue = l>>4, slot = l&15.
    const int row4  = lane >> 4;                      // 0..3
    const int slotb = lane & 15;                      // stored slot
    char* lA = (char*)sA + wave * 32 * 256;           // linear dest
    char* lB = (char*)sB + wave * 32 * 256;

    f32x4 acc[4][4];
#pragma unroll
    for (int m = 0; m < 4; ++m)
#pragma unroll
        for (int n = 0; n < 4; ++n) acc[m][n] = (f32x4){0.f, 0.f, 0.f, 0.f};

    for (int k0 = 0; k0 < D_; k0 += 128) {
#pragma unroll
        for (int q = 0; q < 8; ++q) {
            const int rloc = wave * 32 + q * 4 + row4;          // row in tile
            const int scol = (slotb ^ (((q & 3) * 4 + row4) & 15)) * 8;
            gload16(hb  + (size_t)(rowBase + rloc) * D_ + k0 + scol,
                    lA + q * 1024);
            gload16(wrb + (size_t)(head * HD_ + rloc) * D_ + k0 + scol,
                    lB + q * 1024);
        }
        __syncthreads();   // drains vmcnt(0) before barrier

#pragma unroll
        for (int kk = 0; kk < 4; ++kk) {
            bf16x8 aF[4], bF[4];
#pragma unroll
            for (int m = 0; m < 4; ++m) {
                const int row = wr * 64 + m * 16 + cc;
                const int ks  = (((kk * 4 + g) ^ cc) & 15) * 16;
                aF[m] = *(const bf16x8*)((const char*)sA + row * 256 + ks);
            }
#pragma unroll
            for (int n = 0; n < 4; ++n) {
                const int row = wc * 64 + n * 16 + cc;
                const int ks  = (((kk * 4 + g) ^ cc) & 15) * 16;
                bF[n] = *(const bf16x8*)((const char*)sB + row * 256 + ks);
            }
#pragma unroll
            for (int m = 0; m < 4; ++m)
#pragma unroll
                for (int n = 0; n < 4; ++n)
                    acc[m][n] = __builtin_amdgcn_mfma_f32_16x16x32_bf16(
                        aF[m], bF[n], acc[m][n], 0, 0, 0);
        }
        __syncthreads();   // protect LDS before next stage
    }

    // Epilogue: row = rowBase + wr*64 + m*16 + g*4 + reg,
    //           col_in_head = wc*64 + n*16 + cc
    float ar[4];
#pragma unroll
    for (int n = 0; n < 4; ++n) ar[n] = att_r[wc * 64 + n * 16 + cc];

#pragma unroll
    for (int m = 0; m < 4; ++m) {
#pragma unroll
        for (int r = 0; r < 4; ++r) {
            float p = 0.f;
#pragma unroll
            for (int n = 0; n < 4; ++n) {
                float v = acc[m][n][r];
                v = v > 0.f ? v : 0.01f * v;    // leaky
                p += v * ar[n];
            }
            p += __shfl_xor(p, 1); p += __shfl_xor(p, 2);
            p += __shfl_xor(p, 4); p += __shfl_xor(p, 8);
            if (cc == 0) part[wc][wr * 64 + m * 16 + g * 4 + r] = p;
        }
    }
    __syncthreads();
    if (tid < 128) {
        const int grow = rowBase + tid;
        const int b = grow >> 11, j = grow & (N_ - 1);
        sr[(size_t)(b * H_ + head) * N_ + j] = part[0][tid] + part[1][tid];
    }
}

// ---------------------------------------------------------------------------
// Kernel 2: hbar partials with inline softmax stats (L2-resident sr).
//   hp[jc*32 + b*8 + h][d] = sum_{j in chunk jc} exp(sr-mx)/sum * hb[b,j,d]
// Grid dim3(4 dc, 16 jc, 4 b) = 256 blocks.
// ---------------------------------------------------------------------------
__global__ __launch_bounds__(256) void k_hbar(
    const short* __restrict__ hbm, const float* __restrict__ sr,
    float* __restrict__ hp)
{
    const int dc = blockIdx.x;   // 0..3
    const int jc = blockIdx.y;   // 0..15  (128 j each)
    const int b  = blockIdx.z;   // 0..3
    const int tid = threadIdx.x;
    const int d = dc * 256 + tid;

    __shared__ float smx[8], sism[8];
    {
        const int hh = tid >> 5;
        const int sl = tid & 31;
        const float4* row = (const float4*)(sr + (size_t)(b * H_ + hh) * N_);
        float4 v[16];
        float mx = -1e30f;
#pragma unroll
        for (int k = 0; k < 16; ++k) {
            v[k] = row[sl + k * 32];
            mx = fmaxf(fmaxf(mx, fmaxf(v[k].x, v[k].y)), fmaxf(v[k].z, v[k].w));
        }
#pragma unroll
        for (int m = 1; m < 32; m <<= 1) mx = fmaxf(mx, __shfl_xor(mx, m));
        float sum = 0.f;
#pragma unroll
        for (int k = 0; k < 16; ++k)
            sum += expf(v[k].x - mx) + expf(v[k].y - mx) +
                   expf(v[k].z - mx) + expf(v[k].w - mx);
#pragma unroll
        for (int m = 1; m < 32; m <<= 1) sum += __shfl_xor(sum, m);
        if (sl == 0) { smx[hh] = mx; sism[hh] = 1.f / sum; }
    }
    __syncthreads();

    __shared__ float wl[8][128];
    for (int idx = tid; idx < 1024; idx += 256) {
        const int hh = idx >> 7, jj = idx & 127;
        wl[hh][jj] = expf(sr[(size_t)(b * H_ + hh) * N_ + jc * 128 + jj]
                          - smx[hh]) * sism[hh];
    }
    __syncthreads();

    float acc[8] = {0.f, 0.f, 0.f, 0.f, 0.f, 0.f, 0.f, 0.f};
    const short* hp0 = hbm + ((size_t)(b * N_ + jc * 128)) * D_ + d;
#pragma unroll 4
    for (int jj = 0; jj < 128; ++jj) {
        float hv = bf2f((unsigned short)hp0[(size_t)jj * D_]);
#pragma unroll
        for (int hh = 0; hh < 8; ++hh) acc[hh] += wl[hh][jj] * hv;
    }
#pragma unroll
    for (int hh = 0; hh < 8; ++hh)
        hp[((size_t)(jc * 32) + b * 8 + hh) * D_ + d] = acc[hh];
}

// ---------------------------------------------------------------------------
// Kernel 3: fused hp-reduce + ctx. 1024 blocks; block (bh, dg) reduces its
// (b,head) panel from hp into LDS (L2-resident) then computes 4 ctx outputs
// (one per wave) with coalesced Wr rows.
// ---------------------------------------------------------------------------
__global__ __launch_bounds__(256) void k_ctx(
    const float* __restrict__ hp, const float* __restrict__ Wr,
    float* __restrict__ ctx)
{
    const int bh = blockIdx.x >> 5;           // 0..31 = b*8 + head
    const int b = bh >> 3, head = bh & 7;
    const int dg = (blockIdx.x & 31) * 4;     // 4 outputs per block
    const int tid = threadIdx.x;
    const int lane = tid & 63, wave = tid >> 6;

    __shared__ float xs[1024];
    float4 s = {0.f, 0.f, 0.f, 0.f};
#pragma unroll
    for (int jc = 0; jc < 16; ++jc) {
        float4 v = ((const float4*)(hp + ((size_t)(jc * 32) + bh) * D_))[tid];
        s.x += v.x; s.y += v.y; s.z += v.z; s.w += v.w;
    }
    ((float4*)xs)[tid] = s;
    __syncthreads();

    const int o = dg + wave;                 // d' within head (0..127)
    const float* wrow = Wr + (size_t)(head * HD_ + o) * D_;
    float acc = 0.f;
#pragma unroll
    for (int it = 0; it < 4; ++it) {
        float4 wv = *(const float4*)(wrow + it * 256 + lane * 4);
        float4 xv = ((const float4*)xs)[it * 64 + lane];
        acc += wv.x * xv.x + wv.y * xv.y + wv.z * xv.z + wv.w * xv.w;
    }
#pragma unroll
    for (int m = 1; m < 64; m <<= 1) acc += __shfl_xor(acc, m);
    if (lane == 0) ctx[(size_t)b * D_ + head * HD_ + o] = acc;
}

// ---------------------------------------------------------------------------
// Kernel 4: fvec[b, o] = sum_e ctx[b,e] * Wf[o,e]  (1024 blocks)
// ---------------------------------------------------------------------------
__global__ __launch_bounds__(256) void k_fvec(
    const float* __restrict__ ctx, const float* __restrict__ Wf,
    float* __restrict__ fvec)
{
    const int o = blockIdx.x * 4 + (threadIdx.x >> 6);   // 0..4095
    const int lane = threadIdx.x & 63;
    const int b = o >> 10, orow = o & 1023;
    const float* x  = ctx + (size_t)b * D_;
    const float* wf = Wf + (size_t)orow * D_;
    float s = 0.f;
#pragma unroll
    for (int it = 0; it < 4; ++it) {
        float4 xv = *(const float4*)(x + it * 256 + lane * 4);
        float4 wv = *(const float4*)(wf + it * 256 + lane * 4);
        s += xv.x * wv.x + xv.y * wv.y + xv.z * wv.z + xv.w * wv.w;
    }
#pragma unroll
    for (int m = 1; m < 64; m <<= 1) s += __shfl_xor(s, m);
    if (lane == 0) fvec[o] = s;
}

// ---------------------------------------------------------------------------
// Kernel 5: out = LayerNorm(hb + fvec[b]) * gamma + beta, one block per row.
// Reads the bf16 copy of h (half the fetch; |err| <= 2^-9|h| ~ 0.008 vs
// threshold 0.1075).
// ---------------------------------------------------------------------------
__global__ __launch_bounds__(256) void k_ln(
    const short* __restrict__ hbm, const float* __restrict__ fvec,
    const float* __restrict__ gamma, const float* __restrict__ beta,
    float* __restrict__ out)
{
    const int row = blockIdx.x;
    const int b = row >> 11;
    const int tid = threadIdx.x;
    const int lane = tid & 63, wave = tid >> 6;

    short4 hv4 = *(const short4*)(hbm + (size_t)row * D_ + tid * 4);
    float4 fv = *(const float4*)(fvec + (size_t)b * D_ + tid * 4);
    const float y0 = bf2f((unsigned short)hv4.x) + fv.x;
    const float y1 = bf2f((unsigned short)hv4.y) + fv.y;
    const float y2 = bf2f((unsigned short)hv4.z) + fv.z;
    const float y3 = bf2f((unsigned short)hv4.w) + fv.w;

    float s = y0 + y1 + y2 + y3;
    float q = y0 * y0 + y1 * y1 + y2 * y2 + y3 * y3;
#pragma unroll
    for (int m = 1; m < 64; m <<= 1) { s += __shfl_xor(s, m); q += __shfl_xor(q, m); }

    __shared__ float rs[4], rq[4];
    if (lane == 0) { rs[wave] = s; rq[wave] = q; }
    __syncthreads();
    s = rs[0] + rs[1] + rs[2] + rs[3];
    q = rq[0] + rq[1] + rq[2] + rq[3];

    const float mu  = s * (1.f / D_);
    const float var = q * (1.f / D_) - mu * mu;
    const float inv = rsqrtf(var + 1e-5f);

    float4 gv = *(const float4*)(gamma + tid * 4);
    float4 bv = *(const float4*)(beta + tid * 4);
    float4 ov;
    ov.x = (y0 - mu) * inv * gv.x + bv.x;
    ov.y = (y1 - mu) * inv * gv.y + bv.y;
    ov.z = (y2 - mu) * inv * gv.z + bv.z;
    ov.w = (y3 - mu) * inv * gv.w + bv.w;
    *(float4*)(out + (size_t)row * D_ + tid * 4) = ov;
}

// ---------------------------------------------------------------------------
extern "C" void kernel_launch(void* const* d_in, const int* in_sizes, int n_in,
                              void* d_out, int out_size, void* d_ws, size_t ws_size,
                              hipStream_t stream) {
    const float* h     = (const float*)d_in[0];
    // d_in[1] = Wl  : dead (softmax over additive scores cancels sl)
    const float* Wr    = (const float*)d_in[2];
    // d_in[3] = att_l : dead
    const float* att_r = (const float*)d_in[4];
    const float* Wf    = (const float*)d_in[5];
    const float* gamma = (const float*)d_in[6];
    const float* beta  = (const float*)d_in[7];
    float* out = (float*)d_out;

    char* ws = (char*)d_ws;
    float* sr    = (float*)(ws);                  // B*H*N      = 256 KB
    float* hp    = (float*)(ws + 524288);         // 2 MB
    float* ctx   = (float*)(ws + 2752512);        // 16 KB
    float* fvec  = (float*)(ws + 2768896);        // 16 KB
    short* hb    = (short*)(ws + 4194304);        // 16 MB bf16 h
    short* wrb   = (short*)(ws + 4194304 + 16777216); // 2 MB bf16 Wr

    k_cvt<<<4096 + 512, 256, 0, stream>>>(h, hb, Wr, wrb);
    k_proj_sr<<<dim3(B_ * N_ / 128, H_), 256, 0, stream>>>(hb, wrb, att_r, sr);
    k_hbar<<<dim3(4, 16, 4), 256, 0, stream>>>(hb, sr, hp);
    k_ctx<<<1024, 256, 0, stream>>>(hp, Wr, ctx);
    k_fvec<<<1024, 256, 0, stream>>>(ctx, Wf, fvec);
    k_ln<<<B_ * N_, 256, 0, stream>>>(hb, fvec, gamma, beta, out);
}